// Round 1
// baseline (207.376 us; speedup 1.0000x reference)
//
#include <hip/hip_runtime.h>

// QuantumRegressionModel: 16-qubit statevector, 3 layers x (16 rotations + CNOT chain),
// PauliZ features + linear head. Batch 64, DIM 65536, fp32.
//
// Key reductions:
//  * Rotations within a layer commute (distinct qubits) -> apply in any grouping.
//  * CNOT chain == Gray-code gather: psi_new[j] = psi_old[j ^ (j>>1)].
//  * Features fused into last pass (final state never written).
//
// Wire q <-> global index bit (15-q). State stored as separate re/im fp32 planes.
// Phase A tile: bits {15,14,13} U {0..9}   (block = bits 12,11,10)  -> wires 0,1,2,6..15, in-place.
// Phase B tile: bits {0..12}               (block = bits 15,14,13)  -> wires 3,4,5 + permutation.
//   Source tile for output block (j15,j14,j13) is (j15, j15^j14, j14^j13); within-tile
//   gather index: gl = (j ^ (j>>1)) ^ (j13<<12). Out-of-place (ping-pong ws <-> d_in).

struct G8 { float r00,i00,r01,i01,r10,i10,r11,i11; };

__device__ __forceinline__ G8 loadG(const float* __restrict__ p) {
  G8 g;
  g.r00=p[0]; g.i00=p[1]; g.r01=p[2]; g.i01=p[3];
  g.r10=p[4]; g.i10=p[5]; g.r11=p[6]; g.i11=p[7];
  return g;
}

// (x0,x1) <- U * (x0,x1), complex 2x2
__device__ __forceinline__ void applyG(const G8& g, float2& x0, float2& x1) {
  const float y0r = g.r00*x0.x - g.i00*x0.y + g.r01*x1.x - g.i01*x1.y;
  const float y0i = g.r00*x0.y + g.i00*x0.x + g.r01*x1.y + g.i01*x1.x;
  const float y1r = g.r10*x0.x - g.i10*x0.y + g.r11*x1.x - g.i11*x1.y;
  const float y1i = g.r10*x0.y + g.i10*x0.x + g.r11*x1.y + g.i11*x1.x;
  x0.x=y0r; x0.y=y0i; x1.x=y1r; x1.y=y1i;
}

// Build 48 fused unitaries U = Rz(tz)Ry(ty)Rx(tx); zero feats accumulator.
__global__ void kPrep(const float* __restrict__ vp, float* __restrict__ U,
                      float* __restrict__ feats) {
  const int i = threadIdx.x;
  if (i < 48) {
    const float tx = vp[i*6+0], ty = vp[i*6+1], tz = vp[i*6+2];
    float sx, cx, sy, cy, sz, cz;
    sincosf(0.5f*tx, &sx, &cx);
    sincosf(0.5f*ty, &sy, &cy);
    sincosf(0.5f*tz, &sz, &cz);
    // M = Ry*Rx
    const float m00r = cy*cx,  m00i = sy*sx;
    const float m01r = -sy*cx, m01i = -cy*sx;
    const float m10r = sy*cx,  m10i = -cy*sx;
    const float m11r = cy*cx,  m11i = -sy*sx;
    // row0 *= (cz - i sz), row1 *= (cz + i sz)
    float* o = U + i*8;
    o[0] = cz*m00r + sz*m00i;  o[1] = cz*m00i - sz*m00r;
    o[2] = cz*m01r + sz*m01i;  o[3] = cz*m01i - sz*m01r;
    o[4] = cz*m10r - sz*m10i;  o[5] = cz*m10i + sz*m10r;
    o[6] = cz*m11r - sz*m11i;  o[7] = cz*m11i + sz*m11r;
  }
  for (int j = i; j < 1024; j += 64) feats[j] = 0.f;
}

// Phase A: wires {0,1,2,6..15}. lds bit 12..10 = global bit 15..13; lds bit 9..0 = global 9..0.
__global__ void __launch_bounds__(256) kA(const float* __restrict__ sr, const float* __restrict__ si,
                                          float* __restrict__ dr, float* __restrict__ di,
                                          const float* __restrict__ Ul) {
  __shared__ float2 amp[8192];
  const int t = threadIdx.x;
  const int b = blockIdx.x >> 3;
  const int chunk = blockIdx.x & 7;         // global bits 12,11,10
  const size_t base = ((size_t)b << 16) | ((size_t)chunk << 10);
  #pragma unroll
  for (int s = 0; s < 8; ++s) {             // s = global bits 15,14,13
    const float* pr = sr + base + (s << 13);
    const float* pi = si + base + (s << 13);
    #pragma unroll
    for (int k = 0; k < 1024; k += 256)
      amp[(s << 10) + k + t] = make_float2(pr[k + t], pi[k + t]);
  }
  __syncthreads();
  // 6 double gates on lds bit pairs (12,11),(10,9),(8,7),(6,5),(4,3),(2,1)
  #pragma unroll
  for (int gi = 0; gi < 6; ++gi) {
    const int ta = 12 - 2*gi;
    const int tb = ta - 1;
    const int wa = (ta >= 10) ? (12 - ta) : (15 - ta);
    const int wb = (tb >= 10) ? (12 - tb) : (15 - tb);
    const G8 A = loadG(Ul + wa*8);
    const G8 B = loadG(Ul + wb*8);
    const int mb = (1 << tb) - 1;
    for (int p = t; p < 2048; p += 256) {
      const int i00 = ((p >> tb) << (tb + 2)) | (p & mb);
      const int i01 = i00 | (1 << tb);
      const int i10 = i00 | (2 << tb);
      const int i11 = i00 | (3 << tb);
      float2 x00 = amp[i00], x01 = amp[i01], x10 = amp[i10], x11 = amp[i11];
      applyG(A, x00, x10); applyG(A, x01, x11);   // gate on bit ta
      applyG(B, x00, x01); applyG(B, x10, x11);   // gate on bit tb
      amp[i00]=x00; amp[i01]=x01; amp[i10]=x10; amp[i11]=x11;
    }
    __syncthreads();
  }
  { // single gate on lds bit 0 (wire 15)
    const G8 A = loadG(Ul + 15*8);
    for (int p = t; p < 4096; p += 256) {
      const int i0 = p << 1, i1 = i0 | 1;
      float2 x0 = amp[i0], x1 = amp[i1];
      applyG(A, x0, x1);
      amp[i0]=x0; amp[i1]=x1;
    }
    __syncthreads();
  }
  #pragma unroll
  for (int s = 0; s < 8; ++s) {
    float* pr = dr + base + (s << 13);
    float* pi = di + base + (s << 13);
    #pragma unroll
    for (int k = 0; k < 1024; k += 256) {
      const float2 v = amp[(s << 10) + k + t];
      pr[k + t] = v.x; pi[k + t] = v.y;
    }
  }
}

// Shared body for phase B: load source tile + apply wires 3,4,5. Returns block coords.
__device__ __forceinline__ void loadAndGateB(const float* __restrict__ sr,
                                             const float* __restrict__ si,
                                             const float* __restrict__ Ul,
                                             float2* amp, int t, int b,
                                             int j15, int j14, int j13) {
  const int s = (j15 << 2) | ((j15 ^ j14) << 1) | (j14 ^ j13);  // source tile
  const float* pr = sr + ((size_t)b << 16) + (s << 13);
  const float* pi = si + ((size_t)b << 16) + (s << 13);
  #pragma unroll
  for (int k = 0; k < 8192; k += 256)
    amp[k + t] = make_float2(pr[k + t], pi[k + t]);
  __syncthreads();
  { // double gate: wire 3 (lds bit 12), wire 4 (lds bit 11)
    const G8 A = loadG(Ul + 3*8);
    const G8 B = loadG(Ul + 4*8);
    for (int p = t; p < 2048; p += 256) {
      const int i00 = p;                       // bits 12,11 clear for p < 2048
      const int i01 = i00 | (1 << 11);
      const int i10 = i00 | (2 << 11);
      const int i11 = i00 | (3 << 11);
      float2 x00 = amp[i00], x01 = amp[i01], x10 = amp[i10], x11 = amp[i11];
      applyG(A, x00, x10); applyG(A, x01, x11);
      applyG(B, x00, x01); applyG(B, x10, x11);
      amp[i00]=x00; amp[i01]=x01; amp[i10]=x10; amp[i11]=x11;
    }
    __syncthreads();
  }
  { // single gate: wire 5 (lds bit 10)
    const G8 A = loadG(Ul + 5*8);
    for (int p = t; p < 4096; p += 256) {
      const int i0 = ((p >> 10) << 11) | (p & 1023);
      const int i1 = i0 | 1024;
      float2 x0 = amp[i0], x1 = amp[i1];
      applyG(A, x0, x1);
      amp[i0]=x0; amp[i1]=x1;
    }
    __syncthreads();
  }
}

// Phase B (layers 0,1): gates 3,4,5 + Gray permutation, out-of-place.
__global__ void __launch_bounds__(256) kB(const float* __restrict__ sr, const float* __restrict__ si,
                                          float* __restrict__ dr, float* __restrict__ di,
                                          const float* __restrict__ Ul) {
  __shared__ float2 amp[8192];
  const int t = threadIdx.x;
  const int b   = blockIdx.x >> 3;
  const int j15 = (blockIdx.x >> 2) & 1;
  const int j14 = (blockIdx.x >> 1) & 1;
  const int j13 = blockIdx.x & 1;
  loadAndGateB(sr, si, Ul, amp, t, b, j15, j14, j13);
  float* qr = dr + ((size_t)b << 16) + (j15 << 15) + (j14 << 14) + (j13 << 13);
  float* qi = di + ((size_t)b << 16) + (j15 << 15) + (j14 << 14) + (j13 << 13);
  const int xw = j13 << 12;
  for (int j = t; j < 8192; j += 256) {
    const int gl = (j ^ (j >> 1)) ^ xw;      // CNOT chain == Gray gather
    const float2 v = amp[gl];
    qr[j] = v.x; qi[j] = v.y;
  }
}

// Phase B final layer: gates 3,4,5 + permutation fused into PauliZ feature reduction.
__global__ void __launch_bounds__(256) kBF(const float* __restrict__ sr, const float* __restrict__ si,
                                           const float* __restrict__ Ul,
                                           float* __restrict__ feats) {
  __shared__ float2 amp[8192];
  const int t = threadIdx.x;
  const int b   = blockIdx.x >> 3;
  const int j15 = (blockIdx.x >> 2) & 1;
  const int j14 = (blockIdx.x >> 1) & 1;
  const int j13 = blockIdx.x & 1;
  loadAndGateB(sr, si, Ul, amp, t, b, j15, j14, j13);
  // j = (j15<<15)|(j14<<14)|(j13<<13)| (k<<8) | t ; signs by bits of j (wire q <-> bit 15-q)
  const int xw = j13 << 12;
  float T=0.f, D0=0.f, D1=0.f, D2=0.f, D3=0.f, D4=0.f;
  #pragma unroll
  for (int k = 0; k < 32; ++k) {
    const int j = t + (k << 8);
    const int gl = (j ^ (j >> 1)) ^ xw;
    const float2 v = amp[gl];
    const float p = v.x*v.x + v.y*v.y;
    T += p;
    if (k & 1)  D0 -= p; else D0 += p;   // bit 8  -> wire 7
    if (k & 2)  D1 -= p; else D1 += p;   // bit 9  -> wire 6
    if (k & 4)  D2 -= p; else D2 += p;   // bit 10 -> wire 5
    if (k & 8)  D3 -= p; else D3 += p;   // bit 11 -> wire 4
    if (k & 16) D4 -= p; else D4 += p;   // bit 12 -> wire 3
  }
  float f[16];
  f[0] = j15 ? -T : T;
  f[1] = j14 ? -T : T;
  f[2] = j13 ? -T : T;
  f[3] = D4; f[4] = D3; f[5] = D2; f[6] = D1; f[7] = D0;
  #pragma unroll
  for (int q = 8; q < 16; ++q)
    f[q] = ((t >> (15 - q)) & 1) ? -T : T;
  #pragma unroll
  for (int q = 0; q < 16; ++q) {
    float v = f[q];
    v += __shfl_xor(v, 32); v += __shfl_xor(v, 16); v += __shfl_xor(v, 8);
    v += __shfl_xor(v, 4);  v += __shfl_xor(v, 2);  v += __shfl_xor(v, 1);
    f[q] = v;
  }
  __syncthreads();                 // amp reads done; reuse LDS for cross-wave reduce
  float* sf = (float*)amp;
  const int w = t >> 6;
  if ((t & 63) == 0) {
    #pragma unroll
    for (int q = 0; q < 16; ++q) sf[w*16 + q] = f[q];
  }
  __syncthreads();
  if (t < 16) {
    const float v = sf[t] + sf[16 + t] + sf[32 + t] + sf[48 + t];
    atomicAdd(&feats[b*16 + t], v);
  }
}

__global__ void kHead(const float* __restrict__ feats, const float* __restrict__ w,
                      const float* __restrict__ bias, float* __restrict__ out) {
  const int b = threadIdx.x;
  if (b < 64) {
    float v = bias[0];
    #pragma unroll
    for (int q = 0; q < 16; ++q) v += feats[b*16 + q] * w[q];
    out[b] = v;
  }
}

extern "C" void kernel_launch(void* const* d_in, const int* in_sizes, int n_in,
                              void* d_out, int out_size, void* d_ws, size_t ws_size,
                              hipStream_t stream) {
  float* in_r = (float*)d_in[0];          // (64, 65536) fp32 — clobbered; harness restores
  float* in_i = (float*)d_in[1];
  const float* vp = (const float*)d_in[2];  // (3,16,6)
  const float* hw = (const float*)d_in[3];  // (1,16)
  const float* hb = (const float*)d_in[4];  // (1,)
  float* out = (float*)d_out;               // (64,) fp32

  float* ws_r  = (float*)d_ws;              // 4,194,304 floats
  float* ws_i  = ws_r + 4194304ull;         // 4,194,304 floats
  float* Ubuf  = ws_i + 4194304ull;         // 48*8 floats
  float* feats = Ubuf + 384;                // 64*16 floats

  kPrep<<<1, 64, 0, stream>>>(vp, Ubuf, feats);
  // layer 0
  kA <<<512, 256, 0, stream>>>(in_r, in_i, in_r, in_i, Ubuf + 0*128);
  kB <<<512, 256, 0, stream>>>(in_r, in_i, ws_r, ws_i, Ubuf + 0*128);
  // layer 1
  kA <<<512, 256, 0, stream>>>(ws_r, ws_i, ws_r, ws_i, Ubuf + 1*128);
  kB <<<512, 256, 0, stream>>>(ws_r, ws_i, in_r, in_i, Ubuf + 1*128);
  // layer 2
  kA <<<512, 256, 0, stream>>>(in_r, in_i, in_r, in_i, Ubuf + 2*128);
  kBF<<<512, 256, 0, stream>>>(in_r, in_i, Ubuf + 2*128, feats);
  kHead<<<1, 64, 0, stream>>>(feats, hw, hb, out);
}

// Round 2
// 198.707 us; speedup vs baseline: 1.0436x; 1.0436x over previous
//
#include <hip/hip_runtime.h>

// QuantumRegressionModel: 16-qubit statevector, 3 layers x (16 rotations + CNOT chain),
// PauliZ features + linear head. Batch 64, DIM 65536, fp32.
//
// Reductions:
//  * Rotations in a layer commute -> split wires {5..15} (kP, per-wave subcube) and
//    wires {0..4} (kQ, per-thread 5-bit local cube).
//  * CNOT chain == Gray gather psi_new[j] = psi_old[j ^ (j>>1)] -> folded into the NEXT
//    kernel's load addressing (coalesced: permutation within aligned 64-float windows).
//  * Features on pre-perm state: sign_q(m) = (-1)^{parity(m >> (15-q))} (gray-decode),
//    which factorizes over (k-bits, thread-bits) -> fused into final kQ. No LDS gather.
//  * Final state never materialized.
//
// Wire q <-> global index bit (15-q). State = separate re/im fp32 planes.
// kP layout: wave owns bits {10..0}; per-thread local bits {10,9,8}=k, {1,0}=e (float4 I/O);
//            lane bits {7..2} -> shuffle gates. Register gates: wires 5,6,7 (bits 10..8),
//            wires 14,15 (bits 1,0). Shuffle gates: wires 8..13 (bits 7..2).
// kQ layout: thread owns bits {15..11} (wires 0..4); thread id = bits {7..0}; block = batch x bits {10..8}.

struct G8 { float r00,i00,r01,i01,r10,i10,r11,i11; };

__device__ __forceinline__ G8 loadG(const float* __restrict__ p) {
  G8 g;
  g.r00=p[0]; g.i00=p[1]; g.r01=p[2]; g.i01=p[3];
  g.r10=p[4]; g.i10=p[5]; g.r11=p[6]; g.i11=p[7];
  return g;
}

// complex 2x2: (x0,x1) <- U * (x0,x1), scalars by reference
__device__ __forceinline__ void cmul2(const G8& g, float& r0, float& i0, float& r1, float& i1) {
  const float nr0 = g.r00*r0 - g.i00*i0 + g.r01*r1 - g.i01*i1;
  const float ni0 = g.r00*i0 + g.i00*r0 + g.r01*i1 + g.i01*r1;
  const float nr1 = g.r10*r0 - g.i10*i0 + g.r11*r1 - g.i11*i1;
  const float ni1 = g.r10*i0 + g.i10*r0 + g.r11*i1 + g.i11*r1;
  r0=nr0; i0=ni0; r1=nr1; i1=ni1;
}

// Build 48 fused unitaries U = Rz(tz)Ry(ty)Rx(tx); zero feats accumulator.
__global__ void kPrep(const float* __restrict__ vp, float* __restrict__ U,
                      float* __restrict__ feats) {
  const int i = threadIdx.x;
  if (i < 48) {
    const float tx = vp[i*6+0], ty = vp[i*6+1], tz = vp[i*6+2];
    float sx, cx, sy, cy, sz, cz;
    sincosf(0.5f*tx, &sx, &cx);
    sincosf(0.5f*ty, &sy, &cy);
    sincosf(0.5f*tz, &sz, &cz);
    const float m00r = cy*cx,  m00i = sy*sx;
    const float m01r = -sy*cx, m01i = -cy*sx;
    const float m10r = sy*cx,  m10i = -cy*sx;
    const float m11r = cy*cx,  m11i = -sy*sx;
    float* o = U + i*8;
    o[0] = cz*m00r + sz*m00i;  o[1] = cz*m00i - sz*m00r;
    o[2] = cz*m01r + sz*m01i;  o[3] = cz*m01i - sz*m01r;
    o[4] = cz*m10r - sz*m10i;  o[5] = cz*m10i + sz*m10r;
    o[6] = cz*m11r - sz*m11i;  o[7] = cz*m11i + sz*m11r;
  }
  for (int j = i; j < 1024; j += 64) feats[j] = 0.f;
}

// kP: wires 5..15 (bits 10..0). One wave = 2048-amp subcube, no LDS, no barriers.
// GATHER=1: fold previous layer's CNOT-chain perm into the load: read src[g(j)], g(j)=j^(j>>1).
template<int GATHER>
__global__ void __launch_bounds__(256) kP(const float* __restrict__ sr, const float* __restrict__ si,
                                          float* __restrict__ dr, float* __restrict__ di,
                                          const float* __restrict__ Ul) {
  const int t = threadIdx.x;
  const int lane = t & 63;
  const int wv = t >> 6;
  const int b = blockIdx.x >> 3;
  const int W = ((blockIdx.x & 7) << 2) | wv;          // bits 15..11
  const size_t bb = (size_t)b << 16;
  const int ebase = (W << 11) | (lane << 2);           // j with k=e=0
  float xr[32], xi[32];                                 // a = k*4 + e

  if (GATHER) {
    // g(j) permutes within the aligned float4: component = gray2(e) ^ (j2<<1), j2 = lane&1.
    const bool sw = (lane & 1);
    #pragma unroll
    for (int k = 0; k < 8; ++k) {
      const int base = ebase | (k << 8);
      const int a4 = (base ^ (base >> 1)) & ~3;
      const float4 vr = *(const float4*)(sr + bb + a4);
      const float4 vi = *(const float4*)(si + bb + a4);
      // gray2 = {0,1,3,2}; sw XORs component index with 2
      xr[k*4+0] = sw ? vr.z : vr.x;  xi[k*4+0] = sw ? vi.z : vi.x;
      xr[k*4+1] = sw ? vr.w : vr.y;  xi[k*4+1] = sw ? vi.w : vi.y;
      xr[k*4+2] = sw ? vr.y : vr.w;  xi[k*4+2] = sw ? vi.y : vi.w;
      xr[k*4+3] = sw ? vr.x : vr.z;  xi[k*4+3] = sw ? vi.x : vi.z;
    }
  } else {
    #pragma unroll
    for (int k = 0; k < 8; ++k) {
      const int base = ebase | (k << 8);
      const float4 vr = *(const float4*)(sr + bb + base);
      const float4 vi = *(const float4*)(si + bb + base);
      xr[k*4+0]=vr.x; xr[k*4+1]=vr.y; xr[k*4+2]=vr.z; xr[k*4+3]=vr.w;
      xi[k*4+0]=vi.x; xi[k*4+1]=vi.y; xi[k*4+2]=vi.z; xi[k*4+3]=vi.w;
    }
  }

  // Register gates on k bits: kb=2 -> bit10 -> wire5; kb=1 -> wire6; kb=0 -> wire7.
  #pragma unroll
  for (int g = 0; g < 3; ++g) {
    const int kb = 2 - g;
    const G8 U = loadG(Ul + (5 + g)*8);
    #pragma unroll
    for (int p = 0; p < 4; ++p) {
      const int k0 = ((p >> kb) << (kb + 1)) | (p & ((1 << kb) - 1));
      const int k1 = k0 | (1 << kb);
      #pragma unroll
      for (int e = 0; e < 4; ++e)
        cmul2(U, xr[k0*4+e], xi[k0*4+e], xr[k1*4+e], xi[k1*4+e]);
    }
  }

  // Shuffle gates on lane bits 5..0 -> bits 7..2 -> wires 8..13.
  #pragma unroll
  for (int g = 0; g < 6; ++g) {
    const int lb = 5 - g;
    const int mask = 1 << lb;
    const G8 U = loadG(Ul + (8 + g)*8);
    const bool hi = (lane >> lb) & 1;
    const float ar = hi ? U.r11 : U.r00, ai = hi ? U.i11 : U.i00;
    const float br = hi ? U.r10 : U.r01, bi = hi ? U.i10 : U.i01;
    #pragma unroll
    for (int a = 0; a < 32; ++a) {
      const float pr = __shfl_xor(xr[a], mask);
      const float pi_ = __shfl_xor(xi[a], mask);
      const float nr = ar*xr[a] - ai*xi[a] + br*pr - bi*pi_;
      const float ni = ar*xi[a] + ai*xr[a] + br*pi_ + bi*pr;
      xr[a] = nr; xi[a] = ni;
    }
  }

  // Register gates on e bits: bit1 -> wire14, bit0 -> wire15.
  {
    const G8 U = loadG(Ul + 14*8);
    #pragma unroll
    for (int k = 0; k < 8; ++k) {
      cmul2(U, xr[k*4+0], xi[k*4+0], xr[k*4+2], xi[k*4+2]);
      cmul2(U, xr[k*4+1], xi[k*4+1], xr[k*4+3], xi[k*4+3]);
    }
  }
  {
    const G8 U = loadG(Ul + 15*8);
    #pragma unroll
    for (int k = 0; k < 8; ++k) {
      cmul2(U, xr[k*4+0], xi[k*4+0], xr[k*4+1], xi[k*4+1]);
      cmul2(U, xr[k*4+2], xi[k*4+2], xr[k*4+3], xi[k*4+3]);
    }
  }

  #pragma unroll
  for (int k = 0; k < 8; ++k) {
    const int base = ebase | (k << 8);
    float4 vr, vi;
    vr.x=xr[k*4+0]; vr.y=xr[k*4+1]; vr.z=xr[k*4+2]; vr.w=xr[k*4+3];
    vi.x=xi[k*4+0]; vi.y=xi[k*4+1]; vi.z=xi[k*4+2]; vi.w=xi[k*4+3];
    *(float4*)(dr + bb + base) = vr;
    *(float4*)(di + bb + base) = vi;
  }
}

// kQ: wires 0..4 (bits 15..11), 32 amps/thread, in-place.
__global__ void __launch_bounds__(256) kQ(float* __restrict__ r, float* __restrict__ im,
                                          const float* __restrict__ Ul) {
  const int t = threadIdx.x;
  const int b = blockIdx.x >> 3, c = blockIdx.x & 7;       // c = bits 10..8
  const size_t base = ((size_t)b << 16) | (c << 8) | t;
  float xr[32], xi[32];
  #pragma unroll
  for (int k = 0; k < 32; ++k) { xr[k] = r[base + (k << 11)]; xi[k] = im[base + (k << 11)]; }
  #pragma unroll
  for (int g = 0; g < 5; ++g) {                            // wire g on k-bit 4-g (bit 15-g)
    const int kb = 4 - g;
    const G8 U = loadG(Ul + g*8);
    #pragma unroll
    for (int p = 0; p < 16; ++p) {
      const int i0 = ((p >> kb) << (kb + 1)) | (p & ((1 << kb) - 1));
      const int i1 = i0 | (1 << kb);
      cmul2(U, xr[i0], xi[i0], xr[i1], xi[i1]);
    }
  }
  #pragma unroll
  for (int k = 0; k < 32; ++k) { r[base + (k << 11)] = xr[k]; im[base + (k << 11)] = xi[k]; }
}

// kQF: final-layer kQ + fused PauliZ features (perm folded via gray-decode signs).
// f_q = sum_m |amp(m)|^2 * (-1)^{parity(m >> (15-q))}.
__global__ void __launch_bounds__(256) kQF(const float* __restrict__ r, const float* __restrict__ im,
                                           const float* __restrict__ Ul, float* __restrict__ feats) {
  const int t = threadIdx.x;
  const int b = blockIdx.x >> 3, c = blockIdx.x & 7;
  const size_t base = ((size_t)b << 16) | (c << 8) | t;
  float xr[32], xi[32];
  #pragma unroll
  for (int k = 0; k < 32; ++k) { xr[k] = r[base + (k << 11)]; xi[k] = im[base + (k << 11)]; }
  #pragma unroll
  for (int g = 0; g < 5; ++g) {
    const int kb = 4 - g;
    const G8 U = loadG(Ul + g*8);
    #pragma unroll
    for (int p = 0; p < 16; ++p) {
      const int i0 = ((p >> kb) << (kb + 1)) | (p & ((1 << kb) - 1));
      const int i1 = i0 | (1 << kb);
      cmul2(U, xr[i0], xi[i0], xr[i1], xi[i1]);
    }
  }
  // Signs for wires 0..4 depend only on k = m[15:11]; wires 5..15 = per-thread sign x S11.
  float S15=0.f, S14=0.f, S13=0.f, S12=0.f, S11=0.f;
  #pragma unroll
  for (int k = 0; k < 32; ++k) {
    const float p = xr[k]*xr[k] + xi[k]*xi[k];
    const int b4=(k>>4)&1, b3=(k>>3)&1, b2=(k>>2)&1, b1=(k>>1)&1, b0=k&1;
    S15 += b4 ? -p : p;
    S14 += (b4^b3) ? -p : p;
    S13 += (b4^b3^b2) ? -p : p;
    S12 += (b4^b3^b2^b1) ? -p : p;
    S11 += (b4^b3^b2^b1^b0) ? -p : p;
  }
  int v = (c << 8) | t;                       // gray-decode (suffix parity) of low 11 bits
  v ^= v >> 1; v ^= v >> 2; v ^= v >> 4; v ^= v >> 8;
  float f[16];
  f[0]=S15; f[1]=S14; f[2]=S13; f[3]=S12; f[4]=S11;
  #pragma unroll
  for (int q = 5; q < 16; ++q)
    f[q] = ((v >> (15 - q)) & 1) ? -S11 : S11;
  #pragma unroll
  for (int q = 0; q < 16; ++q) {
    float s = f[q];
    s += __shfl_xor(s, 32); s += __shfl_xor(s, 16); s += __shfl_xor(s, 8);
    s += __shfl_xor(s, 4);  s += __shfl_xor(s, 2);  s += __shfl_xor(s, 1);
    f[q] = s;
  }
  __shared__ float sf[64];
  const int w = t >> 6;
  if ((t & 63) == 0) {
    #pragma unroll
    for (int q = 0; q < 16; ++q) sf[w*16 + q] = f[q];
  }
  __syncthreads();
  if (t < 16) {
    const float s = sf[t] + sf[16 + t] + sf[32 + t] + sf[48 + t];
    atomicAdd(&feats[b*16 + t], s);
  }
}

__global__ void kHead(const float* __restrict__ feats, const float* __restrict__ w,
                      const float* __restrict__ bias, float* __restrict__ out) {
  const int b = threadIdx.x;
  if (b < 64) {
    float v = bias[0];
    #pragma unroll
    for (int q = 0; q < 16; ++q) v += feats[b*16 + q] * w[q];
    out[b] = v;
  }
}

extern "C" void kernel_launch(void* const* d_in, const int* in_sizes, int n_in,
                              void* d_out, int out_size, void* d_ws, size_t ws_size,
                              hipStream_t stream) {
  float* in_r = (float*)d_in[0];            // (64, 65536) fp32 — clobbered; harness restores
  float* in_i = (float*)d_in[1];
  const float* vp = (const float*)d_in[2];  // (3,16,6)
  const float* hw = (const float*)d_in[3];  // (1,16)
  const float* hb = (const float*)d_in[4];  // (1,)
  float* out = (float*)d_out;               // (64,) fp32

  float* ws_r  = (float*)d_ws;              // 4,194,304 floats
  float* ws_i  = ws_r + 4194304ull;
  float* Ubuf  = ws_i + 4194304ull;         // 48*8 floats
  float* feats = Ubuf + 384;                // 64*16 floats

  kPrep<<<1, 64, 0, stream>>>(vp, Ubuf, feats);
  // layer 0
  kP<0><<<512, 256, 0, stream>>>(in_r, in_i, ws_r, ws_i, Ubuf + 0*128);
  kQ   <<<512, 256, 0, stream>>>(ws_r, ws_i, Ubuf + 0*128);
  // layer 1 (perm of layer 0 folded into gather-load)
  kP<1><<<512, 256, 0, stream>>>(ws_r, ws_i, in_r, in_i, Ubuf + 1*128);
  kQ   <<<512, 256, 0, stream>>>(in_r, in_i, Ubuf + 1*128);
  // layer 2
  kP<1><<<512, 256, 0, stream>>>(in_r, in_i, ws_r, ws_i, Ubuf + 2*128);
  kQF  <<<512, 256, 0, stream>>>(ws_r, ws_i, Ubuf + 2*128, feats);
  kHead<<<1, 64, 0, stream>>>(feats, hw, hb, out);
}